// Round 2
// baseline (1273.637 us; speedup 1.0000x reference)
//
#include <hip/hip_runtime.h>

#define D_DIM 256
#define K_CODES 8192
#define N_TOK 16384
#define BM 32
#define BN 256
#define BK 16

// ws layout (floats):
// [0, 8192)          e_norm
// [8192, 24576)      codes (int)
// [24576, 32768)     counts (int)   -- zeroed each launch
// [32768]            loss_sum       -- zeroed each launch
// [32769, 49153)     z_norm

// Exact replication of numpy pairwise_sum for sum of squares, n=128 block
// (8 accumulators, combine ((r0+r1)+(r2+r3))+((r4+r5)+(r6+r7))), no FMA contraction.
__device__ __forceinline__ float pw128_sq(const float* a, int stride) {
    float r[8];
    #pragma unroll
    for (int j = 0; j < 8; ++j) { float v = a[j * stride]; r[j] = __fmul_rn(v, v); }
    for (int i = 8; i < 128; i += 8) {
        #pragma unroll
        for (int j = 0; j < 8; ++j) { float v = a[(i + j) * stride]; r[j] = __fadd_rn(r[j], __fmul_rn(v, v)); }
    }
    return __fadd_rn(__fadd_rn(__fadd_rn(r[0], r[1]), __fadd_rn(r[2], r[3])),
                     __fadd_rn(__fadd_rn(r[4], r[5]), __fadd_rn(r[6], r[7])));
}

// numpy pairwise for n=256: split 128 + 128
__device__ __forceinline__ float sumsq256(const float* a, int stride) {
    return __fadd_rn(pw128_sq(a, stride), pw128_sq(a + 128 * stride, stride));
}

__global__ __launch_bounds__(256) void enorm_kernel(const float* __restrict__ embed,
                                                    float* __restrict__ e_norm) {
    int code = blockIdx.x * 256 + threadIdx.x;   // 8192
    e_norm[code] = sumsq256(embed + code * D_DIM, 1);
}

__global__ __launch_bounds__(256) void znorm_kernel(const float* __restrict__ z_e,
                                                    float* __restrict__ z_norm) {
    int n = blockIdx.x * 256 + threadIdx.x;      // 16384, n = b*1024 + h*32 + w
    int b = n >> 10, hw = n & 1023;
    // z_flat[n, d] = z_e[b*262144 + d*1024 + hw]
    z_norm[n] = sumsq256(z_e + b * 262144 + hw, 1024);
}

__global__ __launch_bounds__(256, 2) void argmin_kernel(const float* __restrict__ z_e,
                                                        const float* __restrict__ embed,
                                                        const float* __restrict__ e_norm,
                                                        const float* __restrict__ z_norm,
                                                        int* __restrict__ codes) {
    __shared__ __align__(16) float zs[D_DIM][BM];  // [d][token]
    __shared__ __align__(16) float es[BK][BN];     // [kk][code]

    const int tid = threadIdx.x;
    const int tm = tid >> 5;   // 0..7  -> tokens tm*4 .. tm*4+3
    const int tn = tid & 31;   // 0..31 -> codes  tn*8 .. tn*8+7 (within BN tile)
    const int n0 = blockIdx.x * BM;        // multiple of 32 -> fixed (b, h)
    const int b  = n0 >> 10;
    const int h32 = n0 & 1023;             // h*32

    // stage z tile: zs[d][w] = z_e[(b*256+d)*1024 + h*32 + w]
    {
        int w = tid & 31, d0 = tid >> 5;
        int base = b * 256 * 1024 + h32 + w;
        #pragma unroll 4
        for (int it = 0; it < 32; ++it) {
            int d = d0 + it * 8;
            zs[d][w] = z_e[base + d * 1024];
        }
    }

    float zn[4];
    #pragma unroll
    for (int i = 0; i < 4; ++i) zn[i] = z_norm[n0 + tm * 4 + i];

    float min1[4] = {3.4e38f, 3.4e38f, 3.4e38f, 3.4e38f};
    int   idx[4]  = {0, 0, 0, 0};

    for (int ct = 0; ct < K_CODES / BN; ++ct) {   // 32 tiles of 256 codes
        float acc[4][8] = {};
        const float* eb = embed + (ct * BN + tid) * D_DIM;

        for (int kb = 0; kb < D_DIM / BK; ++kb) { // 16 k-chunks
            __syncthreads();
            // stage es[kk][c]: each thread loads 16 consecutive floats of its code row
            float r[16];
            *reinterpret_cast<float4*>(&r[0])  = *reinterpret_cast<const float4*>(eb + kb * BK + 0);
            *reinterpret_cast<float4*>(&r[4])  = *reinterpret_cast<const float4*>(eb + kb * BK + 4);
            *reinterpret_cast<float4*>(&r[8])  = *reinterpret_cast<const float4*>(eb + kb * BK + 8);
            *reinterpret_cast<float4*>(&r[12]) = *reinterpret_cast<const float4*>(eb + kb * BK + 12);
            #pragma unroll
            for (int kk = 0; kk < BK; ++kk) es[kk][tid] = r[kk];
            __syncthreads();

            #pragma unroll
            for (int kk = 0; kk < BK; ++kk) {
                float4 a4  = *reinterpret_cast<const float4*>(&zs[kb * BK + kk][tm * 4]);
                float4 b04 = *reinterpret_cast<const float4*>(&es[kk][tn * 8]);
                float4 b14 = *reinterpret_cast<const float4*>(&es[kk][tn * 8 + 4]);
                float av[4] = {a4.x, a4.y, a4.z, a4.w};
                float bv[8] = {b04.x, b04.y, b04.z, b04.w, b14.x, b14.y, b14.z, b14.w};
                #pragma unroll
                for (int i = 0; i < 4; ++i)
                    #pragma unroll
                    for (int j = 0; j < 8; ++j)
                        acc[i][j] = fmaf(av[i], bv[j], acc[i][j]);
            }
        }

        // score = fl(fl(znorm + enorm) - fl(2*dot))  -- replicates np fp32 exactly
        #pragma unroll
        for (int j = 0; j < 8; ++j) {
            int c = ct * BN + tn * 8 + j;
            float en = e_norm[c];
            #pragma unroll
            for (int i = 0; i < 4; ++i) {
                float s = __fsub_rn(__fadd_rn(zn[i], en), __fmul_rn(2.0f, acc[i][j]));
                if (s < min1[i]) { min1[i] = s; idx[i] = c; }
            }
        }
    }

    // merge across the 32 code-lanes (tn) within each half-wave; lower index wins ties
    #pragma unroll
    for (int m = 1; m <= 16; m <<= 1) {
        #pragma unroll
        for (int i = 0; i < 4; ++i) {
            float s2 = __shfl_xor(min1[i], m, 64);
            int   i2 = __shfl_xor(idx[i],  m, 64);
            if (s2 < min1[i] || (s2 == min1[i] && i2 < idx[i])) { min1[i] = s2; idx[i] = i2; }
        }
    }
    if (tn == 0) {
        #pragma unroll
        for (int i = 0; i < 4; ++i) codes[n0 + tm * 4 + i] = idx[i];
    }
}

__global__ __launch_bounds__(256) void gather_kernel(const float* __restrict__ z_e,
                                                     const float* __restrict__ embed,
                                                     const int* __restrict__ codes,
                                                     float* __restrict__ out,
                                                     float* __restrict__ loss_sum) {
    int g = blockIdx.x * 256 + threadIdx.x;  // 4194304 elements, d-major
    int d = g >> 14;
    int n = g & 16383;
    int c = codes[n];
    float val = embed[c * D_DIM + d];
    int pos = ((n >> 10) * 256 + d) * 1024 + (n & 1023);
    out[pos] = val;                // z_q_st (forward value == z_q)
    out[4194304 + pos] = val;      // z_q
    float df = val - z_e[pos];
    float sq = df * df;
    #pragma unroll
    for (int m = 1; m < 64; m <<= 1) sq += __shfl_xor(sq, m, 64);
    __shared__ float wsum[4];
    if ((threadIdx.x & 63) == 0) wsum[threadIdx.x >> 6] = sq;
    __syncthreads();
    if (threadIdx.x == 0) atomicAdd(loss_sum, wsum[0] + wsum[1] + wsum[2] + wsum[3]);
}

__global__ __launch_bounds__(256) void codes_kernel(const int* __restrict__ codes,
                                                    float* __restrict__ out,
                                                    int* __restrict__ counts) {
    int n = blockIdx.x * 256 + threadIdx.x;  // 16384
    int c = codes[n];
    out[8388608 + n] = (float)c;
    atomicAdd(&counts[c], 1);
}

__global__ __launch_bounds__(256) void stats_kernel(const int* __restrict__ counts,
                                                    const float* __restrict__ loss_sum,
                                                    float* __restrict__ out) {
    __shared__ double Hs[256];
    __shared__ int us[256];
    double H = 0.0;
    int used = 0;
    for (int k = threadIdx.x; k < K_CODES; k += 256) {
        int cnt = counts[k];
        if (cnt > 0) {
            double p = (double)cnt / 16384.0;
            H -= p * log(p);
            ++used;
        }
    }
    Hs[threadIdx.x] = H; us[threadIdx.x] = used;
    __syncthreads();
    for (int s = 128; s > 0; s >>= 1) {
        if (threadIdx.x < s) { Hs[threadIdx.x] += Hs[threadIdx.x + s]; us[threadIdx.x] += us[threadIdx.x + s]; }
        __syncthreads();
    }
    if (threadIdx.x == 0) {
        float loss = loss_sum[0] / 4194304.0f;
        float usedf = (float)us[0];
        out[8404992 + 0] = loss;                     // codebook_loss
        out[8404992 + 1] = loss;                     // commitment_loss (same forward value)
        out[8404992 + 2] = (float)exp(Hs[0]);        // perplexity
        out[8404992 + 3] = usedf;                    // used_code_count
        out[8404992 + 4] = usedf / 8192.0f;          // used_code_fraction
        out[8404992 + 5] = 1.0f - usedf / 8192.0f;   // dead_code_fraction
    }
}

extern "C" void kernel_launch(void* const* d_in, const int* in_sizes, int n_in,
                              void* d_out, int out_size, void* d_ws, size_t ws_size,
                              hipStream_t stream) {
    const float* z_e   = (const float*)d_in[0];
    const float* embed = (const float*)d_in[1];
    float* out = (float*)d_out;
    float* ws  = (float*)d_ws;

    float* e_norm   = ws;
    int*   codes    = (int*)(ws + 8192);
    int*   counts   = (int*)(ws + 8192 + 16384);
    float* loss_sum = ws + 8192 + 16384 + 8192;
    float* z_norm   = ws + 8192 + 16384 + 8192 + 1;

    // zero counts + loss accumulator (ws is NOT re-poisoned between replays)
    hipMemsetAsync(counts, 0, (8192 + 1) * sizeof(int), stream);

    enorm_kernel<<<K_CODES / 256, 256, 0, stream>>>(embed, e_norm);
    znorm_kernel<<<N_TOK / 256, 256, 0, stream>>>(z_e, z_norm);
    argmin_kernel<<<N_TOK / BM, 256, 0, stream>>>(z_e, embed, e_norm, z_norm, codes);
    gather_kernel<<<4194304 / 256, 256, 0, stream>>>(z_e, embed, codes, out, loss_sum);
    codes_kernel<<<N_TOK / 256, 256, 0, stream>>>(codes, out, counts);
    stats_kernel<<<1, 256, 0, stream>>>(counts, loss_sum, out);
}

// Round 3
// 666.931 us; speedup vs baseline: 1.9097x; 1.9097x over previous
//
#include <hip/hip_runtime.h>

typedef __attribute__((ext_vector_type(8))) short bf16x8;
typedef __attribute__((ext_vector_type(4))) float f32x4;

#define D_DIM 256
#define K_CODES 8192
#define N_TOK 16384
#define MARGIN 4e-4f
#define CAP 96

// ---------- numpy-exact helpers (pairwise sum of squares, n=256) ----------
__device__ __forceinline__ float pw128_sq(const float* a, int stride) {
    float r[8];
    #pragma unroll
    for (int j = 0; j < 8; ++j) { float v = a[j * stride]; r[j] = __fmul_rn(v, v); }
    for (int i = 8; i < 128; i += 8) {
        #pragma unroll
        for (int j = 0; j < 8; ++j) { float v = a[(i + j) * stride]; r[j] = __fadd_rn(r[j], __fmul_rn(v, v)); }
    }
    return __fadd_rn(__fadd_rn(__fadd_rn(r[0], r[1]), __fadd_rn(r[2], r[3])),
                     __fadd_rn(__fadd_rn(r[4], r[5]), __fadd_rn(r[6], r[7])));
}
__device__ __forceinline__ float sumsq256(const float* a, int stride) {
    return __fadd_rn(pw128_sq(a, stride), pw128_sq(a + 128 * stride, stride));
}

__device__ __forceinline__ unsigned f2bf_u(float f) {   // RNE float->bf16 bits
    unsigned u = __float_as_uint(f);
    return (u + 0x7FFFu + ((u >> 16) & 1u)) >> 16;
}

__global__ __launch_bounds__(256) void enorm_kernel(const float* __restrict__ embed,
                                                    float* __restrict__ e_norm) {
    int code = blockIdx.x * 256 + threadIdx.x;
    e_norm[code] = sumsq256(embed + code * D_DIM, 1);
}

__global__ __launch_bounds__(256) void znorm_kernel(const float* __restrict__ z_e,
                                                    float* __restrict__ z_norm) {
    int n = blockIdx.x * 256 + threadIdx.x;
    int b = n >> 10, hw = n & 1023;
    z_norm[n] = sumsq256(z_e + b * 262144 + hw, 1024);
}

__global__ __launch_bounds__(256) void ecvt_kernel(const float* __restrict__ embed,
                                                   ushort* __restrict__ e_bf) {
    int i = blockIdx.x * 256 + threadIdx.x;          // 524288 float4s
    float4 v = reinterpret_cast<const float4*>(embed)[i];
    ushort4 o;
    o.x = (ushort)f2bf_u(v.x); o.y = (ushort)f2bf_u(v.y);
    o.z = (ushort)f2bf_u(v.z); o.w = (ushort)f2bf_u(v.w);
    reinterpret_cast<ushort4*>(e_bf)[i] = o;
}

// ---------- MFMA approx scores + per-token min + candidate collection ----------
__global__ __launch_bounds__(256, 2) void mfma_argmin_kernel(
    const float* __restrict__ z_e, const ushort* __restrict__ e_bf,
    const float* __restrict__ e_norm,
    unsigned* __restrict__ ccount, unsigned* __restrict__ cand)
{
    __shared__ char lds[65536];
    char* zs = lds;               // 32KB: 64 rows x 512B bf16, byte ^= ((row&7)<<4)
    char* es = lds + 32768;       // 2 x 16KB: 256 rows x 64B bf16, slot ^= (code&3)

    const int tid = threadIdx.x;
    const int l   = tid & 63;
    const int wv  = tid >> 6;
    const int col = l & 15;
    const int kg  = l >> 4;
    const int mb  = (int)blockIdx.x >> 1;
    const int slab= (int)blockIdx.x & 1;
    const int n0  = mb * 64;
    const int bb  = n0 >> 10;
    const int hw0 = n0 & 1023;
    const int cs  = slab * 4096;

    // stage z panel: fp32 -> bf16, transpose [d][hw] -> [token][d], swizzled
    {
        const float* zb = z_e + bb * 262144 + hw0 + l;
        int swz = (l & 7) << 4;
        #pragma unroll 4
        for (int it = 0; it < 32; ++it) {
            int d = it * 8 + wv * 2;
            float a0 = zb[d * 1024];
            float a1 = zb[d * 1024 + 1024];
            unsigned pk = f2bf_u(a0) | (f2bf_u(a1) << 16);
            *(unsigned*)(zs + l * 512 + ((d * 2) ^ swz)) = pk;
        }
    }
    // stage chunk 0 (ct=0, kb=0) into buf 0
    #pragma unroll
    for (int j = 0; j < 4; ++j) {
        int code = j * 64 + wv * 16 + (l >> 2);
        int s4 = l & 3;
        const char* src = (const char*)e_bf + (size_t)(cs + code) * 512 + ((s4 ^ (code & 3)) << 4);
        __builtin_amdgcn_global_load_lds(
            (const __attribute__((address_space(1))) unsigned*)src,
            (__attribute__((address_space(3))) unsigned*)(es + wv * 1024 + j * 4096),
            16, 0, 0);
    }
    __syncthreads();

    const int base_b_byte = (wv * 64 + col) * 64 + ((kg ^ (col & 3)) << 4);
    const int a_swz = (col & 7) << 4;

    f32x4 acc[4][4];
    float runmin[4][4];
    #pragma unroll
    for (int i0 = 0; i0 < 4; ++i0)
        #pragma unroll
        for (int i1 = 0; i1 < 4; ++i1) runmin[i0][i1] = 3.4e38f;

    for (int c = 0; c < 128; ++c) {        // chunk = (ct:4b, kb:3b); 16 tiles x 8 ksteps
        int buf = c & 1;
        int kb = c & 7;
        int ct = c >> 3;
        if (c + 1 < 128) {                 // prefetch next chunk -> buf^1
            int ctn = (c + 1) >> 3, kbn = (c + 1) & 7;
            #pragma unroll
            for (int j = 0; j < 4; ++j) {
                int code = j * 64 + wv * 16 + (l >> 2);
                int s4 = l & 3;
                const char* src = (const char*)e_bf
                    + (size_t)(cs + ctn * 256 + code) * 512 + kbn * 64 + ((s4 ^ (code & 3)) << 4);
                __builtin_amdgcn_global_load_lds(
                    (const __attribute__((address_space(1))) unsigned*)src,
                    (__attribute__((address_space(3))) unsigned*)(es + (buf ^ 1) * 16384 + wv * 1024 + j * 4096),
                    16, 0, 0);
            }
        }
        if (kb == 0) {
            #pragma unroll
            for (int rt = 0; rt < 4; ++rt)
                #pragma unroll
                for (int nt = 0; nt < 4; ++nt)
                    acc[rt][nt] = f32x4{0.f, 0.f, 0.f, 0.f};
        }
        bf16x8 afr[4], bfr[4];
        int a_off = (kb * 64 + kg * 16) ^ a_swz;
        #pragma unroll
        for (int rt = 0; rt < 4; ++rt)
            afr[rt] = *(const bf16x8*)(zs + (rt * 16 + col) * 512 + a_off);
        const char* ebuf = es + buf * 16384;
        #pragma unroll
        for (int nt = 0; nt < 4; ++nt)
            bfr[nt] = *(const bf16x8*)(ebuf + base_b_byte + nt * 1024);
        #pragma unroll
        for (int rt = 0; rt < 4; ++rt)
            #pragma unroll
            for (int nt = 0; nt < 4; ++nt)
                acc[rt][nt] = __builtin_amdgcn_mfma_f32_16x16x32_bf16(afr[rt], bfr[nt], acc[rt][nt], 0, 0, 0);

        if (kb == 7) {                     // tile epilogue: scores, min, candidates
            #pragma unroll
            for (int nt = 0; nt < 4; ++nt) {
                float en = e_norm[cs + ct * 256 + wv * 64 + nt * 16 + col];
                #pragma unroll
                for (int rt = 0; rt < 4; ++rt)
                    #pragma unroll
                    for (int r = 0; r < 4; ++r)
                        acc[rt][nt][r] = fmaf(-2.0f, acc[rt][nt][r], en);
            }
            #pragma unroll
            for (int rt = 0; rt < 4; ++rt) {
                #pragma unroll
                for (int r = 0; r < 4; ++r) {
                    float m4 = fminf(fminf(acc[rt][0][r], acc[rt][1][r]),
                                     fminf(acc[rt][2][r], acc[rt][3][r]));
                    float t = m4;
                    t = fminf(t, __shfl_xor(t, 1, 64));
                    t = fminf(t, __shfl_xor(t, 2, 64));
                    t = fminf(t, __shfl_xor(t, 4, 64));
                    t = fminf(t, __shfl_xor(t, 8, 64));
                    float rm = fminf(runmin[rt][r], t);
                    runmin[rt][r] = rm;
                    float thr = rm + MARGIN;
                    if (m4 < thr) {        // rare
                        int token = n0 + rt * 16 + kg * 4 + r;
                        #pragma unroll
                        for (int nt2 = 0; nt2 < 4; ++nt2) {
                            if (acc[rt][nt2][r] < thr) {
                                unsigned p = atomicAdd(&ccount[token], 1u);
                                if (p < CAP)
                                    cand[token * CAP + p] = cs + ct * 256 + wv * 64 + nt2 * 16 + col;
                            }
                        }
                    }
                }
            }
        }
        __syncthreads();
    }
}

// ---------- exact fp32 rescore of candidates (round-2-identical arithmetic) ----------
__global__ __launch_bounds__(256) void rescore_kernel(
    const float* __restrict__ z_e, const float* __restrict__ embed,
    const float* __restrict__ e_norm, const float* __restrict__ z_norm,
    const unsigned* __restrict__ ccount, const unsigned* __restrict__ cand,
    int* __restrict__ codes)
{
    __shared__ float zrow[4][256];
    int wv = threadIdx.x >> 6, l = threadIdx.x & 63;
    int n = blockIdx.x * 4 + wv;
    int b = n >> 10, hw = n & 1023;
    const float* zb = z_e + b * 262144 + hw;
    #pragma unroll
    for (int j = 0; j < 4; ++j) zrow[wv][l * 4 + j] = zb[(l * 4 + j) * 1024];
    __syncthreads();

    unsigned cnt = ccount[n]; if (cnt > CAP) cnt = CAP;
    float best = 3.4e38f; int bidx = 0x7FFFFFFF;
    float zn = z_norm[n];
    for (unsigned base = 0; base < cnt; base += 64) {
        unsigned i = base + (unsigned)l;
        float s = 3.4e38f; int idx = 0x7FFFFFFF;
        if (i < cnt) {
            idx = (int)cand[n * CAP + i];
            const float* er = embed + idx * D_DIM;
            float dot = 0.f;
            for (int d = 0; d < 256; d += 4) {      // ascending-d fmaf chain == round-2 order
                dot = fmaf(zrow[wv][d],     er[d],     dot);
                dot = fmaf(zrow[wv][d + 1], er[d + 1], dot);
                dot = fmaf(zrow[wv][d + 2], er[d + 2], dot);
                dot = fmaf(zrow[wv][d + 3], er[d + 3], dot);
            }
            s = __fsub_rn(__fadd_rn(zn, e_norm[idx]), __fmul_rn(2.0f, dot));
        }
        if (s < best || (s == best && idx < bidx)) { best = s; bidx = idx; }
    }
    #pragma unroll
    for (int m = 1; m < 64; m <<= 1) {
        float s2 = __shfl_xor(best, m, 64);
        int   i2 = __shfl_xor(bidx, m, 64);
        if (s2 < best || (s2 == best && i2 < bidx)) { best = s2; bidx = i2; }
    }
    if (l == 0) codes[n] = bidx;
}

// ---------- outputs ----------
__global__ __launch_bounds__(256) void gather_kernel(const float* __restrict__ z_e,
                                                     const float* __restrict__ embed,
                                                     const int* __restrict__ codes,
                                                     float* __restrict__ out,
                                                     float* __restrict__ loss_sum) {
    int g = blockIdx.x * 256 + threadIdx.x;  // 4194304 elements, d-major
    int d = g >> 14;
    int n = g & 16383;
    int c = codes[n];
    float val = embed[c * D_DIM + d];
    int pos = ((n >> 10) * 256 + d) * 1024 + (n & 1023);
    out[pos] = val;
    out[4194304 + pos] = val;
    float df = val - z_e[pos];
    float sq = df * df;
    #pragma unroll
    for (int m = 1; m < 64; m <<= 1) sq += __shfl_xor(sq, m, 64);
    __shared__ float wsum[4];
    if ((threadIdx.x & 63) == 0) wsum[threadIdx.x >> 6] = sq;
    __syncthreads();
    if (threadIdx.x == 0) atomicAdd(loss_sum, wsum[0] + wsum[1] + wsum[2] + wsum[3]);
}

__global__ __launch_bounds__(256) void codes_kernel(const int* __restrict__ codes,
                                                    float* __restrict__ out,
                                                    int* __restrict__ counts) {
    int n = blockIdx.x * 256 + threadIdx.x;
    int c = codes[n];
    out[8388608 + n] = (float)c;
    atomicAdd(&counts[c], 1);
}

__global__ __launch_bounds__(256) void stats_kernel(const int* __restrict__ counts,
                                                    const float* __restrict__ loss_sum,
                                                    float* __restrict__ out) {
    __shared__ double Hs[256];
    __shared__ int us[256];
    double H = 0.0; int used = 0;
    for (int k = threadIdx.x; k < K_CODES; k += 256) {
        int cnt = counts[k];
        if (cnt > 0) { double p = (double)cnt / 16384.0; H -= p * log(p); ++used; }
    }
    Hs[threadIdx.x] = H; us[threadIdx.x] = used;
    __syncthreads();
    for (int s = 128; s > 0; s >>= 1) {
        if (threadIdx.x < s) { Hs[threadIdx.x] += Hs[threadIdx.x + s]; us[threadIdx.x] += us[threadIdx.x + s]; }
        __syncthreads();
    }
    if (threadIdx.x == 0) {
        float loss = loss_sum[0] / 4194304.0f;
        float usedf = (float)us[0];
        out[8404992 + 0] = loss;
        out[8404992 + 1] = loss;
        out[8404992 + 2] = (float)exp(Hs[0]);
        out[8404992 + 3] = usedf;
        out[8404992 + 4] = usedf / 8192.0f;
        out[8404992 + 5] = 1.0f - usedf / 8192.0f;
    }
}

extern "C" void kernel_launch(void* const* d_in, const int* in_sizes, int n_in,
                              void* d_out, int out_size, void* d_ws, size_t ws_size,
                              hipStream_t stream) {
    const float* z_e   = (const float*)d_in[0];
    const float* embed = (const float*)d_in[1];
    float* out = (float*)d_out;
    float* ws  = (float*)d_ws;

    float*    e_norm   = ws;                        // 8192
    float*    z_norm   = ws + 8192;                 // 16384
    int*      codes    = (int*)(ws + 24576);        // 16384
    int*      counts   = (int*)(ws + 40960);        // 8192
    float*    loss_sum = ws + 49152;                // 1
    unsigned* ccount   = (unsigned*)(ws + 49408);   // 16384
    unsigned* cand     = (unsigned*)(ws + 65792);   // 16384*96
    ushort*   e_bf     = (ushort*)(ws + 1638656);   // 8192*256 bf16

    hipMemsetAsync(counts, 0, 8193 * sizeof(int), stream);       // counts + loss_sum
    hipMemsetAsync(ccount, 0, 16384 * sizeof(unsigned), stream);

    enorm_kernel<<<32, 256, 0, stream>>>(embed, e_norm);
    znorm_kernel<<<64, 256, 0, stream>>>(z_e, z_norm);
    ecvt_kernel<<<2048, 256, 0, stream>>>(embed, e_bf);
    mfma_argmin_kernel<<<512, 256, 0, stream>>>(z_e, e_bf, e_norm, ccount, cand);
    rescore_kernel<<<4096, 256, 0, stream>>>(z_e, embed, e_norm, z_norm, ccount, cand, codes);
    gather_kernel<<<16384, 256, 0, stream>>>(z_e, embed, codes, out, loss_sum);
    codes_kernel<<<64, 256, 0, stream>>>(codes, out, counts);
    stats_kernel<<<1, 256, 0, stream>>>(counts, loss_sum, out);
}

// Round 6
// 443.778 us; speedup vs baseline: 2.8700x; 1.5028x over previous
//
#include <hip/hip_runtime.h>

typedef __attribute__((ext_vector_type(8))) short bf16x8;
typedef __attribute__((ext_vector_type(4))) float f32x4;

#define D_DIM 256
#define K_CODES 8192
#define N_TOK 16384
#define MARGIN 4e-4f
#define CAP 96
#define FILT_Q 200u
#define QSCALE 1638400.0f
#define QOFF 0.02f

// ---------- numpy-exact helpers (pairwise sum of squares, n=256) ----------
__device__ __forceinline__ float pw128_sq(const float* a, int stride) {
    float r[8];
    #pragma unroll
    for (int j = 0; j < 8; ++j) { float v = a[j * stride]; r[j] = __fmul_rn(v, v); }
    for (int i = 8; i < 128; i += 8) {
        #pragma unroll
        for (int j = 0; j < 8; ++j) { float v = a[(i + j) * stride]; r[j] = __fadd_rn(r[j], __fmul_rn(v, v)); }
    }
    return __fadd_rn(__fadd_rn(__fadd_rn(r[0], r[1]), __fadd_rn(r[2], r[3])),
                     __fadd_rn(__fadd_rn(r[4], r[5]), __fadd_rn(r[6], r[7])));
}
__device__ __forceinline__ float sumsq256(const float* a, int stride) {
    return __fadd_rn(pw128_sq(a, stride), pw128_sq(a + 128 * stride, stride));
}

__device__ __forceinline__ unsigned f2bf_u(float f) {   // RNE float->bf16 bits
    unsigned u = __float_as_uint(f);
    return (u + 0x7FFFu + ((u >> 16) & 1u)) >> 16;
}

__global__ __launch_bounds__(256) void enorm_kernel(const float* __restrict__ embed,
                                                    float* __restrict__ e_norm) {
    int code = blockIdx.x * 256 + threadIdx.x;
    e_norm[code] = sumsq256(embed + code * D_DIM, 1);
}

__global__ __launch_bounds__(256) void znorm_kernel(const float* __restrict__ z_e,
                                                    float* __restrict__ z_norm) {
    int n = blockIdx.x * 256 + threadIdx.x;
    int b = n >> 10, hw = n & 1023;
    z_norm[n] = sumsq256(z_e + b * 262144 + hw, 1024);
}

__global__ __launch_bounds__(256) void ecvt_kernel(const float* __restrict__ embed,
                                                   ushort* __restrict__ e_bf) {
    int i = blockIdx.x * 256 + threadIdx.x;          // 524288 float4s
    float4 v = reinterpret_cast<const float4*>(embed)[i];
    ushort4 o;
    o.x = (ushort)f2bf_u(v.x); o.y = (ushort)f2bf_u(v.y);
    o.z = (ushort)f2bf_u(v.z); o.w = (ushort)f2bf_u(v.w);
    reinterpret_cast<ushort4*>(e_bf)[i] = o;
}

// ---------- MFMA approx scores (16x16x32, round-3 proven, CAP=96) ----------
// candidate word: (quantized_score:16 | code:16)
__global__ __launch_bounds__(256, 2) void mfma_argmin_kernel(
    const float* __restrict__ z_e, const ushort* __restrict__ e_bf,
    const float* __restrict__ e_norm,
    unsigned* __restrict__ ccount, unsigned* __restrict__ cand)
{
    __shared__ char lds[65536];
    char* zs = lds;               // 32KB: 64 rows x 512B bf16, byte ^= ((row&7)<<4)
    char* es = lds + 32768;       // 2 x 16KB: 256 rows x 64B bf16, slot ^= (code&3)

    const int tid = threadIdx.x;
    const int l   = tid & 63;
    const int wv  = tid >> 6;
    const int col = l & 15;
    const int kg  = l >> 4;
    const int mb  = (int)blockIdx.x >> 1;
    const int slab= (int)blockIdx.x & 1;
    const int n0  = mb * 64;
    const int bb  = n0 >> 10;
    const int hw0 = n0 & 1023;
    const int cs  = slab * 4096;

    // stage z panel: fp32 -> bf16, transpose [d][hw] -> [token][d], swizzled
    {
        const float* zb = z_e + bb * 262144 + hw0 + l;
        int swz = (l & 7) << 4;
        #pragma unroll 4
        for (int it = 0; it < 32; ++it) {
            int d = it * 8 + wv * 2;
            float a0 = zb[d * 1024];
            float a1 = zb[d * 1024 + 1024];
            unsigned pk = f2bf_u(a0) | (f2bf_u(a1) << 16);
            *(unsigned*)(zs + l * 512 + ((d * 2) ^ swz)) = pk;
        }
    }
    // stage chunk 0 (ct=0, kb=0) into buf 0
    #pragma unroll
    for (int j = 0; j < 4; ++j) {
        int code = j * 64 + wv * 16 + (l >> 2);
        int s4 = l & 3;
        const char* src = (const char*)e_bf + (size_t)(cs + code) * 512 + ((s4 ^ (code & 3)) << 4);
        __builtin_amdgcn_global_load_lds(
            (const __attribute__((address_space(1))) unsigned*)src,
            (__attribute__((address_space(3))) unsigned*)(es + wv * 1024 + j * 4096),
            16, 0, 0);
    }
    __syncthreads();

    const int base_b_byte = (wv * 64 + col) * 64 + ((kg ^ (col & 3)) << 4);
    const int a_swz = (col & 7) << 4;

    f32x4 acc[4][4];
    float runmin[4][4];
    #pragma unroll
    for (int i0 = 0; i0 < 4; ++i0)
        #pragma unroll
        for (int i1 = 0; i1 < 4; ++i1) runmin[i0][i1] = 3.4e38f;

    for (int c = 0; c < 128; ++c) {        // chunk = (ct:4b, kb:3b); 16 tiles x 8 ksteps
        int buf = c & 1;
        int kb = c & 7;
        int ct = c >> 3;
        if (c + 1 < 128) {                 // prefetch next chunk -> buf^1
            int ctn = (c + 1) >> 3, kbn = (c + 1) & 7;
            #pragma unroll
            for (int j = 0; j < 4; ++j) {
                int code = j * 64 + wv * 16 + (l >> 2);
                int s4 = l & 3;
                const char* src = (const char*)e_bf
                    + (size_t)(cs + ctn * 256 + code) * 512 + kbn * 64 + ((s4 ^ (code & 3)) << 4);
                __builtin_amdgcn_global_load_lds(
                    (const __attribute__((address_space(1))) unsigned*)src,
                    (__attribute__((address_space(3))) unsigned*)(es + (buf ^ 1) * 16384 + wv * 1024 + j * 4096),
                    16, 0, 0);
            }
        }
        if (kb == 0) {
            #pragma unroll
            for (int rt = 0; rt < 4; ++rt)
                #pragma unroll
                for (int nt = 0; nt < 4; ++nt)
                    acc[rt][nt] = f32x4{0.f, 0.f, 0.f, 0.f};
        }
        bf16x8 afr[4], bfr[4];
        int a_off = (kb * 64 + kg * 16) ^ a_swz;
        #pragma unroll
        for (int rt = 0; rt < 4; ++rt)
            afr[rt] = *(const bf16x8*)(zs + (rt * 16 + col) * 512 + a_off);
        const char* ebuf = es + buf * 16384;
        #pragma unroll
        for (int nt = 0; nt < 4; ++nt)
            bfr[nt] = *(const bf16x8*)(ebuf + base_b_byte + nt * 1024);
        #pragma unroll
        for (int rt = 0; rt < 4; ++rt)
            #pragma unroll
            for (int nt = 0; nt < 4; ++nt)
                acc[rt][nt] = __builtin_amdgcn_mfma_f32_16x16x32_bf16(afr[rt], bfr[nt], acc[rt][nt], 0, 0, 0);

        if (kb == 7) {                     // tile epilogue: scores, min, candidates
            #pragma unroll
            for (int nt = 0; nt < 4; ++nt) {
                float en = e_norm[cs + ct * 256 + wv * 64 + nt * 16 + col];
                #pragma unroll
                for (int rt = 0; rt < 4; ++rt)
                    #pragma unroll
                    for (int r = 0; r < 4; ++r)
                        acc[rt][nt][r] = fmaf(-2.0f, acc[rt][nt][r], en);
            }
            #pragma unroll
            for (int rt = 0; rt < 4; ++rt) {
                #pragma unroll
                for (int r = 0; r < 4; ++r) {
                    float m4 = fminf(fminf(acc[rt][0][r], acc[rt][1][r]),
                                     fminf(acc[rt][2][r], acc[rt][3][r]));
                    float t = m4;
                    t = fminf(t, __shfl_xor(t, 1, 64));
                    t = fminf(t, __shfl_xor(t, 2, 64));
                    t = fminf(t, __shfl_xor(t, 4, 64));
                    t = fminf(t, __shfl_xor(t, 8, 64));
                    float rm = fminf(runmin[rt][r], t);
                    runmin[rt][r] = rm;
                    float thr = rm + MARGIN;
                    if (m4 < thr) {        // rare
                        int token = n0 + rt * 16 + kg * 4 + r;
                        #pragma unroll
                        for (int nt2 = 0; nt2 < 4; ++nt2) {
                            float s = acc[rt][nt2][r];
                            if (s < thr) {
                                unsigned p = atomicAdd(&ccount[token], 1u);
                                if (p < CAP) {
                                    int q = (int)((s + QOFF) * QSCALE);
                                    q = q < 0 ? 0 : (q > 65535 ? 65535 : q);
                                    cand[token * CAP + p] = ((unsigned)q << 16)
                                        | (unsigned)(cs + ct * 256 + wv * 64 + nt2 * 16 + col);
                                }
                            }
                        }
                    }
                }
            }
        }
        __syncthreads();
    }
}

// ---------- filter by quantized approx score, exact fp32 rescore of survivors ----------
__global__ __launch_bounds__(256) void rescore_kernel(
    const float* __restrict__ z_e, const float* __restrict__ embed,
    const float* __restrict__ e_norm, const float* __restrict__ z_norm,
    const unsigned* __restrict__ ccount, const unsigned* __restrict__ cand,
    int* __restrict__ codes, float* __restrict__ out, int* __restrict__ counts)
{
    __shared__ float zrow[4][256];
    int wv = threadIdx.x >> 6, l = threadIdx.x & 63;
    int n = blockIdx.x * 4 + wv;
    int b = n >> 10, hw = n & 1023;
    const float* zb = z_e + b * 262144 + hw;
    #pragma unroll
    for (int j = 0; j < 4; ++j) zrow[wv][l * 4 + j] = zb[(l * 4 + j) * 1024];
    __syncthreads();

    unsigned cnt = ccount[n]; if (cnt > CAP) cnt = CAP;
    unsigned c0 = ((unsigned)l      < cnt) ? cand[n * CAP + l]      : 0xFFFFFFFFu;
    unsigned c1 = ((unsigned)l + 64 < cnt) ? cand[n * CAP + l + 64] : 0xFFFFFFFFu;
    unsigned qm = min(c0 >> 16, c1 >> 16);
    #pragma unroll
    for (int m = 1; m < 64; m <<= 1) qm = min(qm, (unsigned)__shfl_xor((int)qm, m, 64));
    unsigned qthr = qm + FILT_Q;

    float best = 3.4e38f; int bidx = 0x7FFFFFFF;
    float zn = z_norm[n];
    #pragma unroll
    for (int pass = 0; pass < 2; ++pass) {
        unsigned cd = pass ? c1 : c0;
        if ((cd >> 16) <= qthr) {          // ~1-2 survivors per token
            int idx = (int)(cd & 0xFFFFu);
            const float* er = embed + idx * D_DIM;
            float dot = 0.f;
            for (int d = 0; d < 256; d += 4) {  // ascending-d fmaf chain (bit-identical to round-2)
                float4 e4 = *reinterpret_cast<const float4*>(er + d);
                dot = fmaf(zrow[wv][d],     e4.x, dot);
                dot = fmaf(zrow[wv][d + 1], e4.y, dot);
                dot = fmaf(zrow[wv][d + 2], e4.z, dot);
                dot = fmaf(zrow[wv][d + 3], e4.w, dot);
            }
            float s = __fsub_rn(__fadd_rn(zn, e_norm[idx]), __fmul_rn(2.0f, dot));
            if (s < best || (s == best && idx < bidx)) { best = s; bidx = idx; }
        }
    }
    #pragma unroll
    for (int m = 1; m < 64; m <<= 1) {      // min with lowest-index tie-break
        float s2 = __shfl_xor(best, m, 64);
        int   i2 = __shfl_xor(bidx, m, 64);
        if (s2 < best || (s2 == best && i2 < bidx)) { best = s2; bidx = i2; }
    }
    if (l == 0) {
        codes[n] = bidx;
        out[8388608 + n] = (float)bidx;
        atomicAdd(&counts[bidx], 1);
    }
}

// ---------- outputs ----------
__global__ __launch_bounds__(256) void gather_kernel(const float* __restrict__ z_e,
                                                     const float* __restrict__ embed,
                                                     const int* __restrict__ codes,
                                                     float* __restrict__ out,
                                                     float* __restrict__ loss_sum) {
    int g = blockIdx.x * 256 + threadIdx.x;  // 1048576 threads, 4 tokens each
    int d = g >> 12;
    int n4 = (g & 4095) * 4;
    int4 c4 = *reinterpret_cast<const int4*>(codes + n4);
    float4 v;
    v.x = embed[c4.x * D_DIM + d];
    v.y = embed[c4.y * D_DIM + d];
    v.z = embed[c4.z * D_DIM + d];
    v.w = embed[c4.w * D_DIM + d];
    int pos = ((n4 >> 10) * 256 + d) * 1024 + (n4 & 1023);
    *reinterpret_cast<float4*>(out + pos) = v;
    *reinterpret_cast<float4*>(out + 4194304 + pos) = v;
    float4 z4 = *reinterpret_cast<const float4*>(z_e + pos);
    float dx = v.x - z4.x, dy = v.y - z4.y, dz = v.z - z4.z, dw = v.w - z4.w;
    float sq = dx * dx + dy * dy + dz * dz + dw * dw;
    #pragma unroll
    for (int m = 1; m < 64; m <<= 1) sq += __shfl_xor(sq, m, 64);
    __shared__ float wsum[4];
    if ((threadIdx.x & 63) == 0) wsum[threadIdx.x >> 6] = sq;
    __syncthreads();
    if (threadIdx.x == 0) atomicAdd(loss_sum, wsum[0] + wsum[1] + wsum[2] + wsum[3]);
}

__global__ __launch_bounds__(256) void stats_kernel(const int* __restrict__ counts,
                                                    const float* __restrict__ loss_sum,
                                                    float* __restrict__ out) {
    __shared__ double Hs[256];
    __shared__ int us[256];
    double H = 0.0; int used = 0;
    for (int k = threadIdx.x; k < K_CODES; k += 256) {
        int cnt = counts[k];
        if (cnt > 0) { double p = (double)cnt / 16384.0; H -= p * log(p); ++used; }
    }
    Hs[threadIdx.x] = H; us[threadIdx.x] = used;
    __syncthreads();
    for (int s = 128; s > 0; s >>= 1) {
        if (threadIdx.x < s) { Hs[threadIdx.x] += Hs[threadIdx.x + s]; us[threadIdx.x] += us[threadIdx.x + s]; }
        __syncthreads();
    }
    if (threadIdx.x == 0) {
        float loss = loss_sum[0] / 4194304.0f;
        float usedf = (float)us[0];
        out[8404992 + 0] = loss;
        out[8404992 + 1] = loss;
        out[8404992 + 2] = (float)exp(Hs[0]);
        out[8404992 + 3] = usedf;
        out[8404992 + 4] = usedf / 8192.0f;
        out[8404992 + 5] = 1.0f - usedf / 8192.0f;
    }
}

extern "C" void kernel_launch(void* const* d_in, const int* in_sizes, int n_in,
                              void* d_out, int out_size, void* d_ws, size_t ws_size,
                              hipStream_t stream) {
    const float* z_e   = (const float*)d_in[0];
    const float* embed = (const float*)d_in[1];
    float* out = (float*)d_out;
    float* ws  = (float*)d_ws;

    float*    e_norm   = ws;                         // [0, 8192)
    float*    z_norm   = ws + 8192;                  // [8192, 24576)
    int*      codes    = (int*)(ws + 24576);         // [24576, 40960)
    int*      counts   = (int*)(ws + 40960);         // [40960, 49152)
    float*    loss_sum = ws + 49152;                 // [49152]
    unsigned* ccount   = (unsigned*)(ws + 49408);    // [49408, 65792)
    unsigned* cand     = (unsigned*)(ws + 65792);    // 16384*96*4B -> [65792, 1638656)
    ushort*   e_bf     = (ushort*)(ws + 1638656);    // 8192*256*2B -> [1638656, 2687232)

    hipMemsetAsync(counts, 0, 8193 * sizeof(int), stream);        // counts + loss_sum
    hipMemsetAsync(ccount, 0, 16384 * sizeof(unsigned), stream);

    enorm_kernel<<<32, 256, 0, stream>>>(embed, e_norm);
    znorm_kernel<<<64, 256, 0, stream>>>(z_e, z_norm);
    ecvt_kernel<<<2048, 256, 0, stream>>>(embed, e_bf);
    mfma_argmin_kernel<<<512, 256, 0, stream>>>(z_e, e_bf, e_norm, ccount, cand);
    rescore_kernel<<<4096, 256, 0, stream>>>(z_e, embed, e_norm, z_norm, ccount, cand, codes, out, counts);
    gather_kernel<<<4096, 256, 0, stream>>>(z_e, embed, codes, out, loss_sum);
    stats_kernel<<<1, 256, 0, stream>>>(counts, loss_sum, out);
}

// Round 7
// 431.987 us; speedup vs baseline: 2.9483x; 1.0273x over previous
//
#include <hip/hip_runtime.h>

typedef __attribute__((ext_vector_type(8))) short bf16x8;
typedef __attribute__((ext_vector_type(4))) float f32x4;

#define D_DIM 256
#define K_CODES 8192
#define N_TOK 16384
#define MARGIN 4e-4f
#define CAP 96
#define FILT_Q 200u
#define QSCALE 1638400.0f
#define QOFF 0.02f

// ---------- numpy-exact helpers (pairwise sum of squares, n=256) ----------
__device__ __forceinline__ float pw128_sq(const float* a, int stride) {
    float r[8];
    #pragma unroll
    for (int j = 0; j < 8; ++j) { float v = a[j * stride]; r[j] = __fmul_rn(v, v); }
    for (int i = 8; i < 128; i += 8) {
        #pragma unroll
        for (int j = 0; j < 8; ++j) { float v = a[(i + j) * stride]; r[j] = __fadd_rn(r[j], __fmul_rn(v, v)); }
    }
    return __fadd_rn(__fadd_rn(__fadd_rn(r[0], r[1]), __fadd_rn(r[2], r[3])),
                     __fadd_rn(__fadd_rn(r[4], r[5]), __fadd_rn(r[6], r[7])));
}
__device__ __forceinline__ float sumsq256(const float* a, int stride) {
    return __fadd_rn(pw128_sq(a, stride), pw128_sq(a + 128 * stride, stride));
}

__device__ __forceinline__ unsigned f2bf_u(float f) {   // RNE float->bf16 bits
    unsigned u = __float_as_uint(f);
    return (u + 0x7FFFu + ((u >> 16) & 1u)) >> 16;
}

__global__ __launch_bounds__(256) void enorm_kernel(const float* __restrict__ embed,
                                                    float* __restrict__ e_norm) {
    int code = blockIdx.x * 256 + threadIdx.x;
    e_norm[code] = sumsq256(embed + code * D_DIM, 1);
}

__global__ __launch_bounds__(256) void znorm_kernel(const float* __restrict__ z_e,
                                                    float* __restrict__ z_norm) {
    int n = blockIdx.x * 256 + threadIdx.x;
    int b = n >> 10, hw = n & 1023;
    z_norm[n] = sumsq256(z_e + b * 262144 + hw, 1024);
}

__global__ __launch_bounds__(256) void ecvt_kernel(const float* __restrict__ embed,
                                                   ushort* __restrict__ e_bf) {
    int i = blockIdx.x * 256 + threadIdx.x;          // 524288 float4s
    float4 v = reinterpret_cast<const float4*>(embed)[i];
    ushort4 o;
    o.x = (ushort)f2bf_u(v.x); o.y = (ushort)f2bf_u(v.y);
    o.z = (ushort)f2bf_u(v.z); o.w = (ushort)f2bf_u(v.w);
    reinterpret_cast<ushort4*>(e_bf)[i] = o;
}

// ---------- MFMA approx scores: barrier-free, B direct from global (L2-resident slab) ----------
// candidate word: (quantized_score:16 | code:16)
__global__ __launch_bounds__(256, 2) void mfma_argmin_kernel(
    const float* __restrict__ z_e, const ushort* __restrict__ e_bf,
    const float* __restrict__ e_norm,
    unsigned* __restrict__ ccount, unsigned* __restrict__ cand)
{
    __shared__ char zs[32768];    // 64 token-rows x 512B bf16, byte ^= ((row&7)<<4)

    const int tid = threadIdx.x;
    const int l   = tid & 63;
    const int wv  = tid >> 6;
    const int col = l & 15;
    const int kg  = l >> 4;
    const int mb  = (int)blockIdx.x >> 1;
    const int slab= (int)blockIdx.x & 1;     // slab parity == XCD parity -> 2MB slab L2-resident
    const int n0  = mb * 64;
    const int bb  = n0 >> 10;
    const int hw0 = n0 & 1023;
    const int cs  = slab * 4096 + wv * 1024; // this wave's 1024-code range

    // stage z panel: fp32 -> bf16, transpose [d][hw] -> [token][d], swizzled (round-3 proven)
    {
        const float* zb = z_e + bb * 262144 + hw0 + l;
        int swz = (l & 7) << 4;
        #pragma unroll 4
        for (int it = 0; it < 32; ++it) {
            int d = it * 8 + wv * 2;
            float a0 = zb[d * 1024];
            float a1 = zb[d * 1024 + 1024];
            unsigned pk = f2bf_u(a0) | (f2bf_u(a1) << 16);
            *(unsigned*)(zs + l * 512 + ((d * 2) ^ swz)) = pk;
        }
    }
    __syncthreads();              // the only barrier in this kernel

    const int a_swz = (col & 7) << 4;
    // per-lane B base: byte-identical data to the round-3 LDS path, loaded directly
    const char* bbase = (const char*)e_bf + (size_t)(cs + col) * 512 + kg * 16;
    const float* enb = e_norm + cs + col;

    float runmin[4][4];
    #pragma unroll
    for (int i0 = 0; i0 < 4; ++i0)
        #pragma unroll
        for (int i1 = 0; i1 < 4; ++i1) runmin[i0][i1] = 3.4e38f;

    for (int t = 0; t < 16; ++t) {          // 16 tiles x 64 codes
        float en[4];
        #pragma unroll
        for (int nt = 0; nt < 4; ++nt) en[nt] = enb[t * 64 + nt * 16];

        f32x4 acc[4][4];
        #pragma unroll
        for (int rt = 0; rt < 4; ++rt)
            #pragma unroll
            for (int nt = 0; nt < 4; ++nt)
                acc[rt][nt] = f32x4{0.f, 0.f, 0.f, 0.f};

        #pragma unroll
        for (int kb = 0; kb < 8; ++kb) {    // K = 256 in 8 steps of 32
            bf16x8 afr[4], bfr[4];
            #pragma unroll
            for (int nt = 0; nt < 4; ++nt)
                bfr[nt] = *(const bf16x8*)(bbase + t * 32768 + nt * 8192 + kb * 64);
            int a_off = (kb * 64 + kg * 16) ^ a_swz;
            #pragma unroll
            for (int rt = 0; rt < 4; ++rt)
                afr[rt] = *(const bf16x8*)(zs + (rt * 16 + col) * 512 + a_off);
            #pragma unroll
            for (int rt = 0; rt < 4; ++rt)
                #pragma unroll
                for (int nt = 0; nt < 4; ++nt)
                    acc[rt][nt] = __builtin_amdgcn_mfma_f32_16x16x32_bf16(afr[rt], bfr[nt], acc[rt][nt], 0, 0, 0);
        }

        // tile epilogue: scores, prefix-min, candidate capture (round-3 semantics)
        int cb = cs + t * 64;
        #pragma unroll
        for (int nt = 0; nt < 4; ++nt)
            #pragma unroll
            for (int rt = 0; rt < 4; ++rt)
                #pragma unroll
                for (int r = 0; r < 4; ++r)
                    acc[rt][nt][r] = fmaf(-2.0f, acc[rt][nt][r], en[nt]);
        #pragma unroll
        for (int rt = 0; rt < 4; ++rt) {
            #pragma unroll
            for (int r = 0; r < 4; ++r) {
                float m4 = fminf(fminf(acc[rt][0][r], acc[rt][1][r]),
                                 fminf(acc[rt][2][r], acc[rt][3][r]));
                float tm = m4;
                tm = fminf(tm, __shfl_xor(tm, 1, 64));
                tm = fminf(tm, __shfl_xor(tm, 2, 64));
                tm = fminf(tm, __shfl_xor(tm, 4, 64));
                tm = fminf(tm, __shfl_xor(tm, 8, 64));
                float rm = fminf(runmin[rt][r], tm);
                runmin[rt][r] = rm;
                float thr = rm + MARGIN;
                if (m4 < thr) {             // rare
                    int token = n0 + rt * 16 + kg * 4 + r;
                    #pragma unroll
                    for (int nt2 = 0; nt2 < 4; ++nt2) {
                        float s = acc[rt][nt2][r];
                        if (s < thr) {
                            unsigned p = atomicAdd(&ccount[token], 1u);
                            if (p < CAP) {
                                int q = (int)((s + QOFF) * QSCALE);
                                q = q < 0 ? 0 : (q > 65535 ? 65535 : q);
                                cand[token * CAP + p] = ((unsigned)q << 16)
                                    | (unsigned)(cb + nt2 * 16 + col);
                            }
                        }
                    }
                }
            }
        }
    }
}

// ---------- filter by quantized approx score, exact fp32 rescore of survivors ----------
__global__ __launch_bounds__(256) void rescore_kernel(
    const float* __restrict__ z_e, const float* __restrict__ embed,
    const float* __restrict__ e_norm, const float* __restrict__ z_norm,
    const unsigned* __restrict__ ccount, const unsigned* __restrict__ cand,
    int* __restrict__ codes, float* __restrict__ out, int* __restrict__ counts)
{
    __shared__ float zrow[4][256];
    int wv = threadIdx.x >> 6, l = threadIdx.x & 63;
    int n = blockIdx.x * 4 + wv;
    int b = n >> 10, hw = n & 1023;
    const float* zb = z_e + b * 262144 + hw;
    #pragma unroll
    for (int j = 0; j < 4; ++j) zrow[wv][l * 4 + j] = zb[(l * 4 + j) * 1024];
    __syncthreads();

    unsigned cnt = ccount[n]; if (cnt > CAP) cnt = CAP;
    unsigned c0 = ((unsigned)l      < cnt) ? cand[n * CAP + l]      : 0xFFFFFFFFu;
    unsigned c1 = ((unsigned)l + 64 < cnt) ? cand[n * CAP + l + 64] : 0xFFFFFFFFu;
    unsigned qm = min(c0 >> 16, c1 >> 16);
    #pragma unroll
    for (int m = 1; m < 64; m <<= 1) qm = min(qm, (unsigned)__shfl_xor((int)qm, m, 64));
    unsigned qthr = qm + FILT_Q;

    float best = 3.4e38f; int bidx = 0x7FFFFFFF;
    float zn = z_norm[n];
    #pragma unroll
    for (int pass = 0; pass < 2; ++pass) {
        unsigned cd = pass ? c1 : c0;
        if ((cd >> 16) <= qthr) {          // ~1-2 survivors per token
            int idx = (int)(cd & 0xFFFFu);
            const float* er = embed + idx * D_DIM;
            float dot = 0.f;
            for (int d = 0; d < 256; d += 4) {  // ascending-d fmaf chain (bit-identical to round-2)
                float4 e4 = *reinterpret_cast<const float4*>(er + d);
                dot = fmaf(zrow[wv][d],     e4.x, dot);
                dot = fmaf(zrow[wv][d + 1], e4.y, dot);
                dot = fmaf(zrow[wv][d + 2], e4.z, dot);
                dot = fmaf(zrow[wv][d + 3], e4.w, dot);
            }
            float s = __fsub_rn(__fadd_rn(zn, e_norm[idx]), __fmul_rn(2.0f, dot));
            if (s < best || (s == best && idx < bidx)) { best = s; bidx = idx; }
        }
    }
    #pragma unroll
    for (int m = 1; m < 64; m <<= 1) {      // min with lowest-index tie-break
        float s2 = __shfl_xor(best, m, 64);
        int   i2 = __shfl_xor(bidx, m, 64);
        if (s2 < best || (s2 == best && i2 < bidx)) { best = s2; bidx = i2; }
    }
    if (l == 0) {
        codes[n] = bidx;
        out[8388608 + n] = (float)bidx;
        atomicAdd(&counts[bidx], 1);
    }
}

// ---------- outputs ----------
__global__ __launch_bounds__(256) void gather_kernel(const float* __restrict__ z_e,
                                                     const float* __restrict__ embed,
                                                     const int* __restrict__ codes,
                                                     float* __restrict__ out,
                                                     float* __restrict__ loss_sum) {
    int g = blockIdx.x * 256 + threadIdx.x;  // 1048576 threads, 4 tokens each
    int d = g >> 12;
    int n4 = (g & 4095) * 4;
    int4 c4 = *reinterpret_cast<const int4*>(codes + n4);
    float4 v;
    v.x = embed[c4.x * D_DIM + d];
    v.y = embed[c4.y * D_DIM + d];
    v.z = embed[c4.z * D_DIM + d];
    v.w = embed[c4.w * D_DIM + d];
    int pos = ((n4 >> 10) * 256 + d) * 1024 + (n4 & 1023);
    *reinterpret_cast<float4*>(out + pos) = v;
    *reinterpret_cast<float4*>(out + 4194304 + pos) = v;
    float4 z4 = *reinterpret_cast<const float4*>(z_e + pos);
    float dx = v.x - z4.x, dy = v.y - z4.y, dz = v.z - z4.z, dw = v.w - z4.w;
    float sq = dx * dx + dy * dy + dz * dz + dw * dw;
    #pragma unroll
    for (int m = 1; m < 64; m <<= 1) sq += __shfl_xor(sq, m, 64);
    __shared__ float wsum[4];
    if ((threadIdx.x & 63) == 0) wsum[threadIdx.x >> 6] = sq;
    __syncthreads();
    if (threadIdx.x == 0) atomicAdd(loss_sum, wsum[0] + wsum[1] + wsum[2] + wsum[3]);
}

__global__ __launch_bounds__(256) void stats_kernel(const int* __restrict__ counts,
                                                    const float* __restrict__ loss_sum,
                                                    float* __restrict__ out) {
    __shared__ double Hs[256];
    __shared__ int us[256];
    double H = 0.0; int used = 0;
    for (int k = threadIdx.x; k < K_CODES; k += 256) {
        int cnt = counts[k];
        if (cnt > 0) { double p = (double)cnt / 16384.0; H -= p * log(p); ++used; }
    }
    Hs[threadIdx.x] = H; us[threadIdx.x] = used;
    __syncthreads();
    for (int s = 128; s > 0; s >>= 1) {
        if (threadIdx.x < s) { Hs[threadIdx.x] += Hs[threadIdx.x + s]; us[threadIdx.x] += us[threadIdx.x + s]; }
        __syncthreads();
    }
    if (threadIdx.x == 0) {
        float loss = loss_sum[0] / 4194304.0f;
        float usedf = (float)us[0];
        out[8404992 + 0] = loss;
        out[8404992 + 1] = loss;
        out[8404992 + 2] = (float)exp(Hs[0]);
        out[8404992 + 3] = usedf;
        out[8404992 + 4] = usedf / 8192.0f;
        out[8404992 + 5] = 1.0f - usedf / 8192.0f;
    }
}

extern "C" void kernel_launch(void* const* d_in, const int* in_sizes, int n_in,
                              void* d_out, int out_size, void* d_ws, size_t ws_size,
                              hipStream_t stream) {
    const float* z_e   = (const float*)d_in[0];
    const float* embed = (const float*)d_in[1];
    float* out = (float*)d_out;
    float* ws  = (float*)d_ws;

    float*    e_norm   = ws;                         // [0, 8192)
    float*    z_norm   = ws + 8192;                  // [8192, 24576)
    int*      codes    = (int*)(ws + 24576);         // [24576, 40960)
    int*      counts   = (int*)(ws + 40960);         // [40960, 49152)
    float*    loss_sum = ws + 49152;                 // [49152]
    unsigned* ccount   = (unsigned*)(ws + 49408);    // [49408, 65792)
    unsigned* cand     = (unsigned*)(ws + 65792);    // 16384*96*4B -> [65792, 1638656)
    ushort*   e_bf     = (ushort*)(ws + 1638656);    // 8192*256*2B -> [1638656, 2687232)

    hipMemsetAsync(counts, 0, 8193 * sizeof(int), stream);        // counts + loss_sum
    hipMemsetAsync(ccount, 0, 16384 * sizeof(unsigned), stream);

    enorm_kernel<<<32, 256, 0, stream>>>(embed, e_norm);
    znorm_kernel<<<64, 256, 0, stream>>>(z_e, z_norm);
    ecvt_kernel<<<2048, 256, 0, stream>>>(embed, e_bf);
    mfma_argmin_kernel<<<512, 256, 0, stream>>>(z_e, e_bf, e_norm, ccount, cand);
    rescore_kernel<<<4096, 256, 0, stream>>>(z_e, embed, e_norm, z_norm, ccount, cand, codes, out, counts);
    gather_kernel<<<4096, 256, 0, stream>>>(z_e, embed, codes, out, loss_sum);
    stats_kernel<<<1, 256, 0, stream>>>(counts, loss_sum, out);
}

// Round 8
// 395.639 us; speedup vs baseline: 3.2192x; 1.0919x over previous
//
#include <hip/hip_runtime.h>

typedef __attribute__((ext_vector_type(8))) short bf16x8;
typedef __attribute__((ext_vector_type(4))) float f32x4;

#define D_DIM 256
#define K_CODES 8192
#define N_TOK 16384
#define MARGIN 2.5e-4f
#define CAP 96
#define FILT_Q 200u
#define QSCALE 1638400.0f
#define QOFF 0.02f

// ---------- numpy-exact helpers (pairwise sum of squares, n=256) ----------
__device__ __forceinline__ float pw128_sq(const float* a, int stride) {
    float r[8];
    #pragma unroll
    for (int j = 0; j < 8; ++j) { float v = a[j * stride]; r[j] = __fmul_rn(v, v); }
    for (int i = 8; i < 128; i += 8) {
        #pragma unroll
        for (int j = 0; j < 8; ++j) { float v = a[(i + j) * stride]; r[j] = __fadd_rn(r[j], __fmul_rn(v, v)); }
    }
    return __fadd_rn(__fadd_rn(__fadd_rn(r[0], r[1]), __fadd_rn(r[2], r[3])),
                     __fadd_rn(__fadd_rn(r[4], r[5]), __fadd_rn(r[6], r[7])));
}
__device__ __forceinline__ float sumsq256(const float* a, int stride) {
    return __fadd_rn(pw128_sq(a, stride), pw128_sq(a + 128 * stride, stride));
}

__device__ __forceinline__ unsigned f2bf_u(float f) {   // RNE float->bf16 bits
    unsigned u = __float_as_uint(f);
    return (u + 0x7FFFu + ((u >> 16) & 1u)) >> 16;
}

__global__ __launch_bounds__(256) void enorm_kernel(const float* __restrict__ embed,
                                                    float* __restrict__ e_norm) {
    int code = blockIdx.x * 256 + threadIdx.x;
    e_norm[code] = sumsq256(embed + code * D_DIM, 1);
}

__global__ __launch_bounds__(256) void znorm_kernel(const float* __restrict__ z_e,
                                                    float* __restrict__ z_norm,
                                                    unsigned* __restrict__ cand) {
    int n = blockIdx.x * 256 + threadIdx.x;
    int b = n >> 10, hw = n & 1023;
    z_norm[n] = sumsq256(z_e + b * 262144 + hw, 1024);
    cand[n * CAP + CAP - 1] = 0xFFFFFFFFu;   // init overflow atomicMin slot (every launch)
}

__global__ __launch_bounds__(256) void ecvt_kernel(const float* __restrict__ embed,
                                                   ushort* __restrict__ e_bf) {
    int i = blockIdx.x * 256 + threadIdx.x;          // 524288 float4s
    float4 v = reinterpret_cast<const float4*>(embed)[i];
    ushort4 o;
    o.x = (ushort)f2bf_u(v.x); o.y = (ushort)f2bf_u(v.y);
    o.z = (ushort)f2bf_u(v.z); o.w = (ushort)f2bf_u(v.w);
    reinterpret_cast<ushort4*>(e_bf)[i] = o;
}

// ---------- MFMA approx scores: barrier-free, B direct from L2-resident slab, pipelined ----------
// grid 1024 = 256 token-panels x 4 slabs; slab constant per XCD; 4 blocks/CU.
// candidate word: (quantized_score:16 | code:16); overflow -> atomicMin in slot CAP-1.
__global__ __launch_bounds__(256, 4) void mfma_argmin_kernel(
    const float* __restrict__ z_e, const ushort* __restrict__ e_bf,
    const float* __restrict__ e_norm,
    unsigned* __restrict__ ccount, unsigned* __restrict__ cand)
{
    __shared__ char zs[32768];    // 64 token-rows x 512B bf16, byte ^= ((row&7)<<4)

    const int tid = threadIdx.x;
    const int l   = tid & 63;
    const int wv  = tid >> 6;
    const int col = l & 15;
    const int kg  = l >> 4;
    const int bid = (int)blockIdx.x;
    const int slab= (bid >> 1) & 3;              // == (XCD id)>>1: slab L2-resident per XCD
    const int mb  = ((bid >> 3) << 1) | (bid & 1);  // 0..255
    const int n0  = mb * 64;
    const int bb  = n0 >> 10;
    const int hw0 = n0 & 1023;
    const int cs  = slab * 2048 + wv * 512;      // this wave's 512-code range

    // stage z panel: fp32 -> bf16, transpose [d][hw] -> [token][d], swizzled (round-3 proven)
    {
        const float* zb = z_e + bb * 262144 + hw0 + l;
        int swz = (l & 7) << 4;
        #pragma unroll 4
        for (int it = 0; it < 32; ++it) {
            int d = it * 8 + wv * 2;
            float a0 = zb[d * 1024];
            float a1 = zb[d * 1024 + 1024];
            unsigned pk = f2bf_u(a0) | (f2bf_u(a1) << 16);
            *(unsigned*)(zs + l * 512 + ((d * 2) ^ swz)) = pk;
        }
    }
    __syncthreads();              // the only barrier

    const int a_swz = (col & 7) << 4;
    const char* bbase = (const char*)e_bf + (size_t)(cs + col) * 512 + kg * 16;
    const float* enb = e_norm + cs + col;

    float runmin[4][4];
    #pragma unroll
    for (int i0 = 0; i0 < 4; ++i0)
        #pragma unroll
        for (int i1 = 0; i1 < 4; ++i1) runmin[i0][i1] = 3.4e38f;

    f32x4 acc[4][4];
    bf16x8 bA[4], bB[4];

    // step = t*8 + kb; t in [0,8) tiles of 64 codes, kb in [0,8) K-chunks of 32
    #define LDB(dst, step) { int _t = (step) >> 3, _kb = (step) & 7;                         \
        _Pragma("unroll")                                                                    \
        for (int nt = 0; nt < 4; ++nt)                                                       \
            dst[nt] = *(const bf16x8*)(bbase + _t * 32768 + nt * 8192 + _kb * 64); }

    #define COMPUTE(bf, step) {                                                              \
        int _kb = (step) & 7;                                                                \
        if (_kb == 0) {                                                                      \
            _Pragma("unroll")                                                                \
            for (int rt = 0; rt < 4; ++rt)                                                   \
                _Pragma("unroll")                                                            \
                for (int nt = 0; nt < 4; ++nt) acc[rt][nt] = f32x4{0.f, 0.f, 0.f, 0.f};      \
        }                                                                                    \
        int a_off = (_kb * 64 + kg * 16) ^ a_swz;                                            \
        _Pragma("unroll")                                                                    \
        for (int rt = 0; rt < 4; ++rt) {                                                     \
            bf16x8 afr = *(const bf16x8*)(zs + (rt * 16 + col) * 512 + a_off);               \
            _Pragma("unroll")                                                                \
            for (int nt = 0; nt < 4; ++nt)                                                   \
                acc[rt][nt] = __builtin_amdgcn_mfma_f32_16x16x32_bf16(afr, bf[nt], acc[rt][nt], 0, 0, 0); \
        }                                                                                    \
        if (_kb == 7) {                                                                      \
            int _t = (step) >> 3;                                                            \
            int cb = cs + _t * 64;                                                           \
            float en[4];                                                                     \
            _Pragma("unroll")                                                                \
            for (int nt = 0; nt < 4; ++nt) en[nt] = enb[_t * 64 + nt * 16];                  \
            _Pragma("unroll")                                                                \
            for (int rt = 0; rt < 4; ++rt)                                                   \
                _Pragma("unroll")                                                            \
                for (int nt = 0; nt < 4; ++nt)                                               \
                    _Pragma("unroll")                                                        \
                    for (int r = 0; r < 4; ++r)                                              \
                        acc[rt][nt][r] = fmaf(-2.0f, acc[rt][nt][r], en[nt]);                \
            _Pragma("unroll")                                                                \
            for (int rt = 0; rt < 4; ++rt) {                                                 \
                _Pragma("unroll")                                                            \
                for (int r = 0; r < 4; ++r) {                                                \
                    float m4 = fminf(fminf(acc[rt][0][r], acc[rt][1][r]),                    \
                                     fminf(acc[rt][2][r], acc[rt][3][r]));                   \
                    float tm = m4;                                                           \
                    tm = fminf(tm, __shfl_xor(tm, 1, 64));                                   \
                    tm = fminf(tm, __shfl_xor(tm, 2, 64));                                   \
                    tm = fminf(tm, __shfl_xor(tm, 4, 64));                                   \
                    tm = fminf(tm, __shfl_xor(tm, 8, 64));                                   \
                    float rm = fminf(runmin[rt][r], tm);                                     \
                    runmin[rt][r] = rm;                                                      \
                    float thr = rm + MARGIN;                                                 \
                    if (m4 < thr) {                                                          \
                        int token = n0 + rt * 16 + kg * 4 + r;                               \
                        _Pragma("unroll")                                                    \
                        for (int nt2 = 0; nt2 < 4; ++nt2) {                                  \
                            float s = acc[rt][nt2][r];                                       \
                            if (s < thr) {                                                   \
                                int q = (int)((s + QOFF) * QSCALE);                          \
                                q = q < 0 ? 0 : (q > 65535 ? 65535 : q);                     \
                                unsigned w = ((unsigned)q << 16)                             \
                                           | (unsigned)(cb + nt2 * 16 + col);                \
                                unsigned p = atomicAdd(&ccount[token], 1u);                  \
                                if (p < CAP - 1) cand[token * CAP + p] = w;                  \
                                else atomicMin(&cand[token * CAP + CAP - 1], w);             \
                            }                                                                \
                        }                                                                    \
                    }                                                                        \
                }                                                                            \
            }                                                                                \
        }                                                                                    \
    }

    LDB(bA, 0);
    for (int sp = 0; sp < 32; ++sp) {       // 2 steps per iteration; buffers statically named
        int step = sp * 2;
        LDB(bB, step + 1);
        COMPUTE(bA, step);
        if (step + 2 < 64) LDB(bA, step + 2);
        COMPUTE(bB, step + 1);
    }
    #undef LDB
    #undef COMPUTE
}

// ---------- filter by quantized approx score, exact fp32 rescore of survivors ----------
__global__ __launch_bounds__(256) void rescore_kernel(
    const float* __restrict__ z_e, const float* __restrict__ embed,
    const float* __restrict__ e_norm, const float* __restrict__ z_norm,
    const unsigned* __restrict__ ccount, const unsigned* __restrict__ cand,
    int* __restrict__ codes, float* __restrict__ out, int* __restrict__ counts)
{
    __shared__ float zrow[4][256];
    int wv = threadIdx.x >> 6, l = threadIdx.x & 63;
    int n = blockIdx.x * 4 + wv;
    int b = n >> 10, hw = n & 1023;
    const float* zb = z_e + b * 262144 + hw;
    #pragma unroll
    for (int j = 0; j < 4; ++j) zrow[wv][l * 4 + j] = zb[(l * 4 + j) * 1024];
    __syncthreads();

    unsigned cnt = ccount[n]; if (cnt > CAP) cnt = CAP;
    unsigned c0 = ((unsigned)l      < cnt) ? cand[n * CAP + l]      : 0xFFFFFFFFu;
    unsigned c1 = ((unsigned)l + 64 < cnt) ? cand[n * CAP + l + 64] : 0xFFFFFFFFu;
    unsigned qm = min(c0 >> 16, c1 >> 16);
    #pragma unroll
    for (int m = 1; m < 64; m <<= 1) qm = min(qm, (unsigned)__shfl_xor((int)qm, m, 64));
    unsigned qthr = qm + FILT_Q;

    float best = 3.4e38f; int bidx = 0x7FFFFFFF;
    float zn = z_norm[n];
    #pragma unroll
    for (int pass = 0; pass < 2; ++pass) {
        unsigned cd = pass ? c1 : c0;
        if ((cd >> 16) <= qthr) {          // ~1-2 survivors per token
            int idx = (int)(cd & 0xFFFFu);
            const float* er = embed + idx * D_DIM;
            float dot = 0.f;
            for (int d = 0; d < 256; d += 4) {  // ascending-d fmaf chain (bit-identical to round-2)
                float4 e4 = *reinterpret_cast<const float4*>(er + d);
                dot = fmaf(zrow[wv][d],     e4.x, dot);
                dot = fmaf(zrow[wv][d + 1], e4.y, dot);
                dot = fmaf(zrow[wv][d + 2], e4.z, dot);
                dot = fmaf(zrow[wv][d + 3], e4.w, dot);
            }
            float s = __fsub_rn(__fadd_rn(zn, e_norm[idx]), __fmul_rn(2.0f, dot));
            if (s < best || (s == best && idx < bidx)) { best = s; bidx = idx; }
        }
    }
    #pragma unroll
    for (int m = 1; m < 64; m <<= 1) {      // min with lowest-index tie-break
        float s2 = __shfl_xor(best, m, 64);
        int   i2 = __shfl_xor(bidx, m, 64);
        if (s2 < best || (s2 == best && i2 < bidx)) { best = s2; bidx = i2; }
    }
    if (l == 0) {
        codes[n] = bidx;
        out[8388608 + n] = (float)bidx;
        atomicAdd(&counts[bidx], 1);
    }
}

// ---------- outputs: LDS-staged gather (coalesced embed reads) + fused MSE ----------
__global__ __launch_bounds__(256) void gather_kernel(const float* __restrict__ z_e,
                                                     const float* __restrict__ embed,
                                                     const int* __restrict__ codes,
                                                     float* __restrict__ out,
                                                     float* __restrict__ loss_sum) {
    __shared__ float zq[32][257];   // +1 pad: phase-2 reads stride 257 -> conflict-free
    __shared__ int cds[32];
    const int tid = threadIdx.x;
    const int n0 = blockIdx.x * 32;           // 32 tokens, single b (32 | 1024)
    if (tid < 32) cds[tid] = codes[n0 + tid];
    __syncthreads();
    #pragma unroll 4
    for (int it = 0; it < 32; ++it)           // coalesced 1KB row loads
        zq[it][tid] = embed[cds[it] * D_DIM + tid];
    __syncthreads();

    const int bb = n0 >> 10, hw0 = n0 & 1023;
    const int n32 = tid & 31, dl = tid >> 5;  // dl in 0..7
    float sq = 0.f;
    #pragma unroll 4
    for (int it = 0; it < 32; ++it) {
        int d = it * 8 + dl;
        float v = zq[n32][d];
        int pos = (bb * 256 + d) * 1024 + hw0 + n32;   // 128B-contiguous per 32 lanes
        out[pos] = v;
        out[4194304 + pos] = v;
        float df = v - z_e[pos];
        sq = fmaf(df, df, sq);
    }
    #pragma unroll
    for (int m = 1; m < 64; m <<= 1) sq += __shfl_xor(sq, m, 64);
    __shared__ float wsum[4];
    if ((tid & 63) == 0) wsum[tid >> 6] = sq;
    __syncthreads();
    if (tid == 0) atomicAdd(loss_sum, wsum[0] + wsum[1] + wsum[2] + wsum[3]);
}

__global__ __launch_bounds__(256) void stats_kernel(const int* __restrict__ counts,
                                                    const float* __restrict__ loss_sum,
                                                    float* __restrict__ out) {
    __shared__ double Hs[256];
    __shared__ int us[256];
    double H = 0.0; int used = 0;
    for (int k = threadIdx.x; k < K_CODES; k += 256) {
        int cnt = counts[k];
        if (cnt > 0) { double p = (double)cnt / 16384.0; H -= p * log(p); ++used; }
    }
    Hs[threadIdx.x] = H; us[threadIdx.x] = used;
    __syncthreads();
    for (int s = 128; s > 0; s >>= 1) {
        if (threadIdx.x < s) { Hs[threadIdx.x] += Hs[threadIdx.x + s]; us[threadIdx.x] += us[threadIdx.x + s]; }
        __syncthreads();
    }
    if (threadIdx.x == 0) {
        float loss = loss_sum[0] / 4194304.0f;
        float usedf = (float)us[0];
        out[8404992 + 0] = loss;
        out[8404992 + 1] = loss;
        out[8404992 + 2] = (float)exp(Hs[0]);
        out[8404992 + 3] = usedf;
        out[8404992 + 4] = usedf / 8192.0f;
        out[8404992 + 5] = 1.0f - usedf / 8192.0f;
    }
}

extern "C" void kernel_launch(void* const* d_in, const int* in_sizes, int n_in,
                              void* d_out, int out_size, void* d_ws, size_t ws_size,
                              hipStream_t stream) {
    const float* z_e   = (const float*)d_in[0];
    const float* embed = (const float*)d_in[1];
    float* out = (float*)d_out;
    float* ws  = (float*)d_ws;

    float*    e_norm   = ws;                         // [0, 8192)
    float*    z_norm   = ws + 8192;                  // [8192, 24576)
    int*      codes    = (int*)(ws + 24576);         // [24576, 40960)
    int*      counts   = (int*)(ws + 40960);         // [40960, 49152)
    float*    loss_sum = ws + 49152;                 // [49152]
    unsigned* ccount   = (unsigned*)(ws + 49408);    // [49408, 65792)
    unsigned* cand     = (unsigned*)(ws + 65792);    // 16384*96*4B -> [65792, 1638656)
    ushort*   e_bf     = (ushort*)(ws + 1638656);    // 8192*256*2B -> [1638656, 2687232)

    hipMemsetAsync(counts, 0, 8193 * sizeof(int), stream);        // counts + loss_sum
    hipMemsetAsync(ccount, 0, 16384 * sizeof(unsigned), stream);

    enorm_kernel<<<32, 256, 0, stream>>>(embed, e_norm);
    znorm_kernel<<<64, 256, 0, stream>>>(z_e, z_norm, cand);
    ecvt_kernel<<<2048, 256, 0, stream>>>(embed, e_bf);
    mfma_argmin_kernel<<<1024, 256, 0, stream>>>(z_e, e_bf, e_norm, ccount, cand);
    rescore_kernel<<<4096, 256, 0, stream>>>(z_e, embed, e_norm, z_norm, ccount, cand, codes, out, counts);
    gather_kernel<<<512, 256, 0, stream>>>(z_e, embed, codes, out, loss_sum);
    stats_kernel<<<1, 256, 0, stream>>>(counts, loss_sum, out);
}

// Round 9
// 286.343 us; speedup vs baseline: 4.4479x; 1.3817x over previous
//
#include <hip/hip_runtime.h>

typedef __attribute__((ext_vector_type(8))) short bf16x8;
typedef __attribute__((ext_vector_type(4))) float f32x4;

#define D_DIM 256
#define K_CODES 8192
#define N_TOK 16384
#define MARGIN 2.5e-4f
#define CAP 96
#define LCAP 24
#define FILT_Q 200u
#define QSCALE 1638400.0f
#define QOFF 0.02f

// ---------- numpy-exact helpers (pairwise sum of squares, n=256) ----------
__device__ __forceinline__ float pw128_sq(const float* a, int stride) {
    float r[8];
    #pragma unroll
    for (int j = 0; j < 8; ++j) { float v = a[j * stride]; r[j] = __fmul_rn(v, v); }
    for (int i = 8; i < 128; i += 8) {
        #pragma unroll
        for (int j = 0; j < 8; ++j) { float v = a[(i + j) * stride]; r[j] = __fadd_rn(r[j], __fmul_rn(v, v)); }
    }
    return __fadd_rn(__fadd_rn(__fadd_rn(r[0], r[1]), __fadd_rn(r[2], r[3])),
                     __fadd_rn(__fadd_rn(r[4], r[5]), __fadd_rn(r[6], r[7])));
}
__device__ __forceinline__ float sumsq256(const float* a, int stride) {
    return __fadd_rn(pw128_sq(a, stride), pw128_sq(a + 128 * stride, stride));
}

__device__ __forceinline__ unsigned f2bf_u(float f) {   // RNE float->bf16 bits
    unsigned u = __float_as_uint(f);
    return (u + 0x7FFFu + ((u >> 16) & 1u)) >> 16;
}

__global__ __launch_bounds__(256) void enorm_kernel(const float* __restrict__ embed,
                                                    float* __restrict__ e_norm) {
    int code = blockIdx.x * 256 + threadIdx.x;
    e_norm[code] = sumsq256(embed + code * D_DIM, 1);
}

__global__ __launch_bounds__(256) void znorm_kernel(const float* __restrict__ z_e,
                                                    float* __restrict__ z_norm) {
    int n = blockIdx.x * 256 + threadIdx.x;
    int b = n >> 10, hw = n & 1023;
    z_norm[n] = sumsq256(z_e + b * 262144 + hw, 1024);
}

__global__ __launch_bounds__(256) void ecvt_kernel(const float* __restrict__ embed,
                                                   ushort* __restrict__ e_bf) {
    int i = blockIdx.x * 256 + threadIdx.x;          // 524288 float4s
    float4 v = reinterpret_cast<const float4*>(embed)[i];
    ushort4 o;
    o.x = (ushort)f2bf_u(v.x); o.y = (ushort)f2bf_u(v.y);
    o.z = (ushort)f2bf_u(v.z); o.w = (ushort)f2bf_u(v.w);
    reinterpret_cast<ushort4*>(e_bf)[i] = o;
}

// ---------- MFMA approx scores: barrier-free B from L2-resident slab, LDS-local capture ----------
// grid 1024 = 256 token-panels x 4 slabs; slab constant per XCD; 4 blocks/CU.
// candidate word: (quantized_score:16 | code:16). Capture -> LDS; one flush at end.
// 4 blocks x LCAP(24) = 96 = CAP: global cand can never truncate.
__global__ __launch_bounds__(256, 4) void mfma_argmin_kernel(
    const float* __restrict__ z_e, const ushort* __restrict__ e_bf,
    const float* __restrict__ e_norm,
    unsigned* __restrict__ ccount, unsigned* __restrict__ cand)
{
    __shared__ char zs[32768];    // 64 token-rows x 512B bf16, byte ^= ((row&7)<<4)
    __shared__ unsigned cand_l[64][LCAP];
    __shared__ unsigned cnt_l[64];

    const int tid = threadIdx.x;
    const int l   = tid & 63;
    const int wv  = tid >> 6;
    const int col = l & 15;
    const int kg  = l >> 4;
    const int bid = (int)blockIdx.x;
    const int slab= (bid >> 1) & 3;              // == (XCD id)>>1: slab L2-resident per XCD
    const int mb  = ((bid >> 3) << 1) | (bid & 1);  // 0..255
    const int n0  = mb * 64;
    const int bb  = n0 >> 10;
    const int hw0 = n0 & 1023;
    const int cs  = slab * 2048 + wv * 512;      // this wave's 512-code range

    if (tid < 64) { cnt_l[tid] = 0; cand_l[tid][LCAP - 1] = 0xFFFFFFFFu; }

    // stage z panel: fp32 -> bf16, transpose [d][hw] -> [token][d], swizzled (round-3 proven)
    {
        const float* zb = z_e + bb * 262144 + hw0 + l;
        int swz = (l & 7) << 4;
        #pragma unroll 4
        for (int it = 0; it < 32; ++it) {
            int d = it * 8 + wv * 2;
            float a0 = zb[d * 1024];
            float a1 = zb[d * 1024 + 1024];
            unsigned pk = f2bf_u(a0) | (f2bf_u(a1) << 16);
            *(unsigned*)(zs + l * 512 + ((d * 2) ^ swz)) = pk;
        }
    }
    __syncthreads();

    const int a_swz = (col & 7) << 4;
    const char* bbase = (const char*)e_bf + (size_t)(cs + col) * 512 + kg * 16;
    const float* enb = e_norm + cs + col;

    float runmin[4][4];
    #pragma unroll
    for (int i0 = 0; i0 < 4; ++i0)
        #pragma unroll
        for (int i1 = 0; i1 < 4; ++i1) runmin[i0][i1] = 3.4e38f;

    f32x4 acc[4][4];
    bf16x8 bA[4], bB[4];

    // step = t*8 + kb; t in [0,8) tiles of 64 codes, kb in [0,8) K-chunks of 32
    #define LDB(dst, step) { int _t = (step) >> 3, _kb = (step) & 7;                         \
        _Pragma("unroll")                                                                    \
        for (int nt = 0; nt < 4; ++nt)                                                       \
            dst[nt] = *(const bf16x8*)(bbase + _t * 32768 + nt * 8192 + _kb * 64); }

    #define COMPUTE(bf, step) {                                                              \
        int _kb = (step) & 7;                                                                \
        if (_kb == 0) {                                                                      \
            _Pragma("unroll")                                                                \
            for (int rt = 0; rt < 4; ++rt)                                                   \
                _Pragma("unroll")                                                            \
                for (int nt = 0; nt < 4; ++nt) acc[rt][nt] = f32x4{0.f, 0.f, 0.f, 0.f};      \
        }                                                                                    \
        int a_off = (_kb * 64 + kg * 16) ^ a_swz;                                            \
        _Pragma("unroll")                                                                    \
        for (int rt = 0; rt < 4; ++rt) {                                                     \
            bf16x8 afr = *(const bf16x8*)(zs + (rt * 16 + col) * 512 + a_off);               \
            _Pragma("unroll")                                                                \
            for (int nt = 0; nt < 4; ++nt)                                                   \
                acc[rt][nt] = __builtin_amdgcn_mfma_f32_16x16x32_bf16(afr, bf[nt], acc[rt][nt], 0, 0, 0); \
        }                                                                                    \
        if (_kb == 7) {                                                                      \
            int _t = (step) >> 3;                                                            \
            int cb = cs + _t * 64;                                                           \
            float en[4];                                                                     \
            _Pragma("unroll")                                                                \
            for (int nt = 0; nt < 4; ++nt) en[nt] = enb[_t * 64 + nt * 16];                  \
            _Pragma("unroll")                                                                \
            for (int rt = 0; rt < 4; ++rt)                                                   \
                _Pragma("unroll")                                                            \
                for (int nt = 0; nt < 4; ++nt)                                               \
                    _Pragma("unroll")                                                        \
                    for (int r = 0; r < 4; ++r)                                              \
                        acc[rt][nt][r] = fmaf(-2.0f, acc[rt][nt][r], en[nt]);                \
            _Pragma("unroll")                                                                \
            for (int rt = 0; rt < 4; ++rt) {                                                 \
                _Pragma("unroll")                                                            \
                for (int r = 0; r < 4; ++r) {                                                \
                    float m4 = fminf(fminf(acc[rt][0][r], acc[rt][1][r]),                    \
                                     fminf(acc[rt][2][r], acc[rt][3][r]));                   \
                    float tm = m4;                                                           \
                    tm = fminf(tm, __shfl_xor(tm, 1, 64));                                   \
                    tm = fminf(tm, __shfl_xor(tm, 2, 64));                                   \
                    tm = fminf(tm, __shfl_xor(tm, 4, 64));                                   \
                    tm = fminf(tm, __shfl_xor(tm, 8, 64));                                   \
                    float rm = fminf(runmin[rt][r], tm);                                     \
                    runmin[rt][r] = rm;                                                      \
                    float thr = rm + MARGIN;                                                 \
                    if (m4 < thr) {                                                          \
                        int tl = rt * 16 + kg * 4 + r;       /* block-local token */         \
                        _Pragma("unroll")                                                    \
                        for (int nt2 = 0; nt2 < 4; ++nt2) {                                  \
                            float s = acc[rt][nt2][r];                                       \
                            if (s < thr) {                                                   \
                                int q = (int)((s + QOFF) * QSCALE);                          \
                                q = q < 0 ? 0 : (q > 65535 ? 65535 : q);                     \
                                unsigned w = ((unsigned)q << 16)                             \
                                           | (unsigned)(cb + nt2 * 16 + col);                \
                                unsigned p = atomicAdd(&cnt_l[tl], 1u);     /* LDS atomic */ \
                                if (p < LCAP - 1) cand_l[tl][p] = w;                         \
                                else atomicMin(&cand_l[tl][LCAP - 1], w);                    \
                            }                                                                \
                        }                                                                    \
                    }                                                                        \
                }                                                                            \
            }                                                                                \
        }                                                                                    \
    }

    LDB(bA, 0);
    for (int sp = 0; sp < 32; ++sp) {       // 2 steps per iteration; buffers statically named
        int step = sp * 2;
        LDB(bB, step + 1);
        COMPUTE(bA, step);
        if (step + 2 < 64) LDB(bA, step + 2);
        COMPUTE(bB, step + 1);
    }
    #undef LDB
    #undef COMPUTE

    // flush block-local candidates: one global atomic per token per block
    __syncthreads();
    if (tid < 64) {
        unsigned cl = cnt_l[tid]; if (cl > LCAP) cl = LCAP;
        if (cl) {
            int token = n0 + tid;
            unsigned p = atomicAdd(&ccount[token], cl);
            for (unsigned i = 0; i < cl && p + i < CAP; ++i)
                cand[token * CAP + p + i] = cand_l[tid][i];
        }
    }
}

// ---------- filter by quantized approx score, exact fp32 rescore of survivors ----------
__global__ __launch_bounds__(256) void rescore_kernel(
    const float* __restrict__ z_e, const float* __restrict__ embed,
    const float* __restrict__ e_norm, const float* __restrict__ z_norm,
    const unsigned* __restrict__ ccount, const unsigned* __restrict__ cand,
    int* __restrict__ codes, float* __restrict__ out, int* __restrict__ counts)
{
    __shared__ float zrow[4][256];
    int wv = threadIdx.x >> 6, l = threadIdx.x & 63;
    int n = blockIdx.x * 4 + wv;
    int b = n >> 10, hw = n & 1023;
    const float* zb = z_e + b * 262144 + hw;
    #pragma unroll
    for (int j = 0; j < 4; ++j) zrow[wv][l * 4 + j] = zb[(l * 4 + j) * 1024];
    __syncthreads();

    unsigned cnt = ccount[n]; if (cnt > CAP) cnt = CAP;
    unsigned c0 = ((unsigned)l      < cnt) ? cand[n * CAP + l]      : 0xFFFFFFFFu;
    unsigned c1 = ((unsigned)l + 64 < cnt) ? cand[n * CAP + l + 64] : 0xFFFFFFFFu;
    unsigned qm = min(c0 >> 16, c1 >> 16);
    #pragma unroll
    for (int m = 1; m < 64; m <<= 1) qm = min(qm, (unsigned)__shfl_xor((int)qm, m, 64));
    unsigned qthr = qm + FILT_Q;

    float best = 3.4e38f; int bidx = 0x7FFFFFFF;
    float zn = z_norm[n];
    #pragma unroll
    for (int pass = 0; pass < 2; ++pass) {
        unsigned cd = pass ? c1 : c0;
        if ((cd >> 16) <= qthr) {          // ~1-2 survivors per token
            int idx = (int)(cd & 0xFFFFu);
            const float* er = embed + idx * D_DIM;
            float dot = 0.f;
            for (int d = 0; d < 256; d += 4) {  // ascending-d fmaf chain (bit-identical to round-2)
                float4 e4 = *reinterpret_cast<const float4*>(er + d);
                dot = fmaf(zrow[wv][d],     e4.x, dot);
                dot = fmaf(zrow[wv][d + 1], e4.y, dot);
                dot = fmaf(zrow[wv][d + 2], e4.z, dot);
                dot = fmaf(zrow[wv][d + 3], e4.w, dot);
            }
            float s = __fsub_rn(__fadd_rn(zn, e_norm[idx]), __fmul_rn(2.0f, dot));
            if (s < best || (s == best && idx < bidx)) { best = s; bidx = idx; }
        }
    }
    #pragma unroll
    for (int m = 1; m < 64; m <<= 1) {      // min with lowest-index tie-break
        float s2 = __shfl_xor(best, m, 64);
        int   i2 = __shfl_xor(bidx, m, 64);
        if (s2 < best || (s2 == best && i2 < bidx)) { best = s2; bidx = i2; }
    }
    if (l == 0) {
        codes[n] = bidx;
        out[8388608 + n] = (float)bidx;
        atomicAdd(&counts[bidx], 1);
    }
}

// ---------- outputs: LDS-staged gather (coalesced embed reads) + fused MSE ----------
__global__ __launch_bounds__(256) void gather_kernel(const float* __restrict__ z_e,
                                                     const float* __restrict__ embed,
                                                     const int* __restrict__ codes,
                                                     float* __restrict__ out,
                                                     float* __restrict__ loss_sum) {
    __shared__ float zq[32][257];   // +1 pad: phase-2 reads stride 257 -> conflict-free
    __shared__ int cds[32];
    const int tid = threadIdx.x;
    const int n0 = blockIdx.x * 32;           // 32 tokens, single b (32 | 1024)
    if (tid < 32) cds[tid] = codes[n0 + tid];
    __syncthreads();
    #pragma unroll 4
    for (int it = 0; it < 32; ++it)           // coalesced 1KB row loads
        zq[it][tid] = embed[cds[it] * D_DIM + tid];
    __syncthreads();

    const int bb = n0 >> 10, hw0 = n0 & 1023;
    const int n32 = tid & 31, dl = tid >> 5;  // dl in 0..7
    float sq = 0.f;
    #pragma unroll 4
    for (int it = 0; it < 32; ++it) {
        int d = it * 8 + dl;
        float v = zq[n32][d];
        int pos = (bb * 256 + d) * 1024 + hw0 + n32;   // 128B-contiguous per 32 lanes
        out[pos] = v;
        out[4194304 + pos] = v;
        float df = v - z_e[pos];
        sq = fmaf(df, df, sq);
    }
    #pragma unroll
    for (int m = 1; m < 64; m <<= 1) sq += __shfl_xor(sq, m, 64);
    __shared__ float wsum[4];
    if ((tid & 63) == 0) wsum[tid >> 6] = sq;
    __syncthreads();
    if (tid == 0) atomicAdd(loss_sum, wsum[0] + wsum[1] + wsum[2] + wsum[3]);
}

__global__ __launch_bounds__(256) void stats_kernel(const int* __restrict__ counts,
                                                    const float* __restrict__ loss_sum,
                                                    float* __restrict__ out) {
    __shared__ double Hs[256];
    __shared__ int us[256];
    double H = 0.0; int used = 0;
    for (int k = threadIdx.x; k < K_CODES; k += 256) {
        int cnt = counts[k];
        if (cnt > 0) { double p = (double)cnt / 16384.0; H -= p * log(p); ++used; }
    }
    Hs[threadIdx.x] = H; us[threadIdx.x] = used;
    __syncthreads();
    for (int s = 128; s > 0; s >>= 1) {
        if (threadIdx.x < s) { Hs[threadIdx.x] += Hs[threadIdx.x + s]; us[threadIdx.x] += us[threadIdx.x + s]; }
        __syncthreads();
    }
    if (threadIdx.x == 0) {
        float loss = loss_sum[0] / 4194304.0f;
        float usedf = (float)us[0];
        out[8404992 + 0] = loss;
        out[8404992 + 1] = loss;
        out[8404992 + 2] = (float)exp(Hs[0]);
        out[8404992 + 3] = usedf;
        out[8404992 + 4] = usedf / 8192.0f;
        out[8404992 + 5] = 1.0f - usedf / 8192.0f;
    }
}

extern "C" void kernel_launch(void* const* d_in, const int* in_sizes, int n_in,
                              void* d_out, int out_size, void* d_ws, size_t ws_size,
                              hipStream_t stream) {
    const float* z_e   = (const float*)d_in[0];
    const float* embed = (const float*)d_in[1];
    float* out = (float*)d_out;
    float* ws  = (float*)d_ws;

    float*    e_norm   = ws;                         // [0, 8192)
    float*    z_norm   = ws + 8192;                  // [8192, 24576)
    int*      codes    = (int*)(ws + 24576);         // [24576, 40960)
    int*      counts   = (int*)(ws + 40960);         // [40960, 49152)
    float*    loss_sum = ws + 49152;                 // [49152]
    unsigned* ccount   = (unsigned*)(ws + 49408);    // [49408, 65792)
    unsigned* cand     = (unsigned*)(ws + 65792);    // 16384*96*4B -> [65792, 1638656)
    ushort*   e_bf     = (ushort*)(ws + 1638656);    // 8192*256*2B -> [1638656, 2687232)

    hipMemsetAsync(counts, 0, 8193 * sizeof(int), stream);        // counts + loss_sum
    hipMemsetAsync(ccount, 0, 16384 * sizeof(unsigned), stream);

    enorm_kernel<<<32, 256, 0, stream>>>(embed, e_norm);
    znorm_kernel<<<64, 256, 0, stream>>>(z_e, z_norm);
    ecvt_kernel<<<2048, 256, 0, stream>>>(embed, e_bf);
    mfma_argmin_kernel<<<1024, 256, 0, stream>>>(z_e, e_bf, e_norm, ccount, cand);
    rescore_kernel<<<4096, 256, 0, stream>>>(z_e, embed, e_norm, z_norm, ccount, cand, codes, out, counts);
    gather_kernel<<<512, 256, 0, stream>>>(z_e, embed, codes, out, loss_sum);
    stats_kernel<<<1, 256, 0, stream>>>(counts, loss_sum, out);
}